// Round 1
// baseline (323.906 us; speedup 1.0000x reference)
//
#include <hip/hip_runtime.h>
#include <cstdint>
#include <cstddef>

#define NATOMS 8192
#define DIM 32
#define NSEQ 4096
#define KSPLIT 16
#define BM 256
#define BK 32
#define KPB (NATOMS / KSPLIT)   // 512 k per block
#define NT (KPB / BK)           // 16 tiles

typedef __attribute__((address_space(1))) const void GV;
typedef __attribute__((address_space(3))) void LV;

__device__ __forceinline__ void async16(void* lds, const void* g) {
  __builtin_amdgcn_global_load_lds((GV*)g, (LV*)lds, 16, 0, 0);
}

// ---------------------------------------------------------------------------
// Big GEMM: P[ks] = A[rows, krange] @ h[krange, :]   (fp32, split-K partials)
// ---------------------------------------------------------------------------
__global__ __launch_bounds__(256, 2)
void cpi_gemm(const float* __restrict__ A, const float* __restrict__ h,
              float* __restrict__ P) {
  // 64 KiB static LDS: double-buffered A tile [BM][BK], XOR-swizzled chunks.
  __shared__ float Ab[2][BM * BK];

  const int tid  = threadIdx.x;
  const int wave = tid >> 6;
  const int rb   = blockIdx.x & 31;   // row block 0..31
  const int ks   = blockIdx.x >> 5;   // k split 0..15
  const int row0 = rb * BM;
  const int k0   = ks * KPB;
  const int rg   = tid >> 2;          // 0..63 row group (rows rg + 64j)
  const int cg   = tid & 3;           // 0..3 col group (8 cols each)
  const int lane = tid & 63;

  float acc[4][8];
#pragma unroll
  for (int j = 0; j < 4; ++j)
#pragma unroll
    for (int c = 0; c < 8; ++c) acc[j][c] = 0.f;

  // Stage one A tile (32 KB) with global_load_lds width=16.
  // LDS dest linear; global source chunk pre-swizzled: chunk c of row r
  // holds global chunk (c ^ (r&7))  -> conflict-free b128 reads later.
  auto stageA = [&](int buf, int t) {
    const int kb = k0 + t * BK;
#pragma unroll
    for (int i = 0; i < 8; ++i) {
      const int D = (wave * 8 + i) * 64 + lane;  // 16B chunk index 0..2047
      const int r = D >> 3;
      const int c = D & 7;
      const float* src =
          A + (size_t)(row0 + r) * NATOMS + kb + ((c ^ (r & 7)) << 2);
      async16(&Ab[buf][(wave * 8 + i) * 256], src);  // wave-uniform lds base
    }
  };

  stageA(0, 0);
  asm volatile("s_waitcnt vmcnt(0)" ::: "memory");
  __syncthreads();

  int cur = 0;
#pragma unroll 1
  for (int t = 0; t < NT; ++t) {
    if (t + 1 < NT) stageA(cur ^ 1, t + 1);  // prefetch next tile (async)

    const float* Ac = &Ab[cur][0];
    const float* ht = h + (size_t)(k0 + t * BK) * DIM;
    const int swb = rg & 7;

#pragma unroll
    for (int k4 = 0; k4 < 8; ++k4) {
      const int sw = k4 ^ swb;  // swizzled chunk holding global chunk k4
      float4 a[4];
#pragma unroll
      for (int j = 0; j < 4; ++j)
        a[j] = *(const float4*)(Ac + (rg + 64 * j) * BK + sw * 4);

      float4 h0[4], h1[4];
#pragma unroll
      for (int q = 0; q < 4; ++q) {
        const float* hp = ht + (k4 * 4 + q) * DIM + cg * 8;
        h0[q] = *(const float4*)hp;
        h1[q] = *(const float4*)(hp + 4);
      }

#define DO_Q(AQ, H0, H1)                                          \
  _Pragma("unroll") for (int j = 0; j < 4; ++j) {                 \
    const float av = a[j].AQ;                                     \
    acc[j][0] += av * H0.x; acc[j][1] += av * H0.y;               \
    acc[j][2] += av * H0.z; acc[j][3] += av * H0.w;               \
    acc[j][4] += av * H1.x; acc[j][5] += av * H1.y;               \
    acc[j][6] += av * H1.z; acc[j][7] += av * H1.w;               \
  }
      DO_Q(x, h0[0], h1[0])
      DO_Q(y, h0[1], h1[1])
      DO_Q(z, h0[2], h1[2])
      DO_Q(w, h0[3], h1[3])
#undef DO_Q
    }

    asm volatile("s_waitcnt vmcnt(0)" ::: "memory");
    __syncthreads();
    cur ^= 1;
  }

  float* Pp = P + (size_t)ks * (NATOMS * DIM) + (size_t)row0 * DIM;
#pragma unroll
  for (int j = 0; j < 4; ++j) {
    const int r = rg + 64 * j;
    float4 v0 = make_float4(acc[j][0], acc[j][1], acc[j][2], acc[j][3]);
    float4 v1 = make_float4(acc[j][4], acc[j][5], acc[j][6], acc[j][7]);
    *(float4*)(Pp + (size_t)r * DIM + cg * 8) = v0;
    *(float4*)(Pp + (size_t)r * DIM + cg * 8 + 4) = v1;
  }
}

// ---------------------------------------------------------------------------
// Gather xs = emb_fp[fingerprints], write to out, and h0 = relu(xs@W0 + b0)
// ---------------------------------------------------------------------------
__global__ __launch_bounds__(256)
void cpi_gather_h(const int* __restrict__ fp, const float* __restrict__ embfp,
                  const float* __restrict__ W, const float* __restrict__ b,
                  float* __restrict__ xs, float* __restrict__ hout) {
  __shared__ float xsl[8][DIM];
  __shared__ float Wl[DIM][DIM];
  const int tid = threadIdx.x;
  const int col = tid & 31;
  const int r8  = tid >> 5;
  const int row = blockIdx.x * 8 + r8;
  const int f   = fp[row];
  const float v = embfp[(size_t)f * DIM + col];
  xs[(size_t)row * DIM + col] = v;
  xsl[r8][col] = v;
#pragma unroll
  for (int i = 0; i < 4; ++i) {
    const int idx = tid + i * 256;
    ((float*)Wl)[idx] = W[idx];
  }
  __syncthreads();
  float a = b[col];
#pragma unroll
  for (int d = 0; d < DIM; ++d) a += xsl[r8][d] * Wl[d][col];
  hout[(size_t)row * DIM + col] = fmaxf(a, 0.f);
}

// ---------------------------------------------------------------------------
// xs += sum_s P[s]; optionally h = relu(xs@W + b) for the next layer
// ---------------------------------------------------------------------------
__global__ __launch_bounds__(256)
void cpi_reduce_h(const float* __restrict__ P, const float* __restrict__ W,
                  const float* __restrict__ b, float* __restrict__ xs,
                  float* __restrict__ hout, const int compute_h) {
  __shared__ float xsl[8][DIM];
  __shared__ float Wl[DIM][DIM];
  const int tid = threadIdx.x;
  const int col = tid & 31;
  const int r8  = tid >> 5;
  const int row = blockIdx.x * 8 + r8;
  const size_t off = (size_t)row * DIM + col;
  float s = xs[off];
#pragma unroll
  for (int k = 0; k < KSPLIT; ++k) s += P[(size_t)k * (NATOMS * DIM) + off];
  xs[off] = s;
  if (compute_h) {  // uniform branch
    xsl[r8][col] = s;
#pragma unroll
    for (int i = 0; i < 4; ++i) {
      const int idx = tid + i * 256;
      ((float*)Wl)[idx] = W[idx];
    }
    __syncthreads();
    float a = b[col];
#pragma unroll
    for (int d = 0; d < DIM; ++d) a += xsl[r8][d] * Wl[d][col];
    hout[off] = fmaxf(a, 0.f);
  }
}

// ---------------------------------------------------------------------------
// word_vectors = emb_word[words]
// ---------------------------------------------------------------------------
__global__ __launch_bounds__(256)
void cpi_words(const int* __restrict__ words, const float* __restrict__ embw,
               float* __restrict__ out) {
  const int i = blockIdx.x * 256 + threadIdx.x;
  const int s = i >> 5;
  const int c = i & 31;
  out[i] = embw[(size_t)words[s] * DIM + c];
}

extern "C" void kernel_launch(void* const* d_in, const int* in_sizes, int n_in,
                              void* d_out, int out_size, void* d_ws, size_t ws_size,
                              hipStream_t stream) {
  const int*   fp    = (const int*)d_in[0];
  const float* adj   = (const float*)d_in[1];
  const int*   words = (const int*)d_in[2];
  const float* embfp = (const float*)d_in[3];
  const float* embw  = (const float*)d_in[4];
  const float* Wg    = (const float*)d_in[5];
  const float* bg    = (const float*)d_in[6];

  float* out = (float*)d_out;
  float* xs  = out;                    // [8192*32] = final compound_vector
  float* wv  = out + NATOMS * DIM;     // [4096*32] word vectors
  float* h   = (float*)d_ws;                  // 1 MB
  float* P   = h + NATOMS * DIM;              // 16 MB split-K partials

  cpi_words<<<dim3(NSEQ * DIM / 256), dim3(256), 0, stream>>>(words, embw, wv);
  cpi_gather_h<<<dim3(NATOMS / 8), dim3(256), 0, stream>>>(fp, embfp, Wg, bg, xs, h);

  for (int l = 0; l < 3; ++l) {
    cpi_gemm<<<dim3(KSPLIT * 32), dim3(256), 0, stream>>>(adj, h, P);
    const float* Wn = (l < 2) ? (Wg + (size_t)(l + 1) * DIM * DIM) : Wg;
    const float* bn = (l < 2) ? (bg + (size_t)(l + 1) * DIM) : bg;
    cpi_reduce_h<<<dim3(NATOMS / 8), dim3(256), 0, stream>>>(
        P, Wn, bn, xs, h, (l < 2) ? 1 : 0);
  }
}

// Round 2
// 283.001 us; speedup vs baseline: 1.1445x; 1.1445x over previous
//
#include <hip/hip_runtime.h>
#include <cstdint>
#include <cstddef>

#define NATOMS 8192
#define DIM 32
#define NSEQ 4096
#define KSPLIT 16
#define BM 256
#define BK 32
#define KPB (NATOMS / KSPLIT)   // 512 k per block
#define NT (KPB / BK)           // 16 tiles

typedef __attribute__((address_space(1))) const void GV;
typedef __attribute__((address_space(3))) void LV;

__device__ __forceinline__ void async16(void* lds, const void* g) {
  __builtin_amdgcn_global_load_lds((GV*)g, (LV*)lds, 16, 0, 0);
}

// ---------------------------------------------------------------------------
// Big GEMM: P[ks] = A[rows, krange] @ h[krange, :]   (fp32, split-K partials)
// Wave w owns output cols [w*8, w*8+8) for ALL 256 rows; lane = row (+64j).
// h addresses are wave-uniform -> scalar loads (s_load) -> SGPR fmac operand.
// Compute phase has NO vector-memory ops, so the global_load_lds prefetch for
// tile t+1 stays in flight under the whole compute of tile t (no vmcnt FIFO
// drain), restoring load/compute overlap.
// ---------------------------------------------------------------------------
__global__ __launch_bounds__(256, 2)
void cpi_gemm(const float* __restrict__ A, const float* __restrict__ h,
              float* __restrict__ P) {
  // 64 KiB static LDS: double-buffered A tile [BM][BK], XOR-swizzled chunks.
  __shared__ float Ab[2][BM * BK];

  const int tid  = threadIdx.x;
  const int wave = __builtin_amdgcn_readfirstlane(tid >> 6);  // uniform
  const int lane = tid & 63;
  const int rb   = blockIdx.x & 31;   // row block 0..31
  const int ks   = blockIdx.x >> 5;   // k split 0..15
  const int row0 = rb * BM;
  const int k0   = ks * KPB;

  float acc[4][8];
#pragma unroll
  for (int j = 0; j < 4; ++j)
#pragma unroll
    for (int c = 0; c < 8; ++c) acc[j][c] = 0.f;

  // Stage one A tile (32 KB) with global_load_lds width=16.
  // LDS dest linear; global source chunk pre-swizzled: LDS slot s of row r
  // holds global chunk (s ^ (r&7)) -> conflict-free b128 reads later
  // (8 consecutive lanes = 8 consecutive rows span all 8 bank-quads).
  auto stageA = [&](int buf, int t) {
    const int kb = k0 + t * BK;
#pragma unroll
    for (int i = 0; i < 8; ++i) {
      const int D = (wave * 8 + i) * 64 + lane;  // 16B chunk index 0..2047
      const int r = D >> 3;
      const int c = D & 7;
      const float* src =
          A + (size_t)(row0 + r) * NATOMS + kb + ((c ^ (r & 7)) << 2);
      async16(&Ab[buf][(wave * 8 + i) * 256], src);  // wave-uniform lds base
    }
  };

  stageA(0, 0);
  asm volatile("s_waitcnt vmcnt(0)" ::: "memory");
  __syncthreads();

  int cur = 0;
  const int sb = lane & 7;
#pragma unroll 1
  for (int t = 0; t < NT; ++t) {
    if (t + 1 < NT) stageA(cur ^ 1, t + 1);  // async prefetch, stays in flight

    const float* Ac = &Ab[cur][0];
    // wave-uniform h pointer for this tile (8 cols owned by this wave)
    const float* hw = h + (size_t)(k0 + t * BK) * DIM + wave * 8;

#pragma unroll
    for (int k4 = 0; k4 < 8; ++k4) {
      // 4 k-values x 8 cols of h, uniform addresses -> scalar loads
      float hs[4][8];
#pragma unroll
      for (int kk = 0; kk < 4; ++kk)
#pragma unroll
        for (int c = 0; c < 8; ++c)
          hs[kk][c] = hw[(k4 * 4 + kk) * DIM + c];

      const int slot = k4 ^ sb;  // swizzled 16B slot holding global chunk k4
      float4 a[4];
#pragma unroll
      for (int j = 0; j < 4; ++j)
        a[j] = *(const float4*)(Ac + (lane + 64 * j) * BK + slot * 4);

#pragma unroll
      for (int j = 0; j < 4; ++j) {
#pragma unroll
        for (int c = 0; c < 8; ++c) {
          float s = acc[j][c];
          s += a[j].x * hs[0][c];
          s += a[j].y * hs[1][c];
          s += a[j].z * hs[2][c];
          s += a[j].w * hs[3][c];
          acc[j][c] = s;
        }
      }
    }

    asm volatile("s_waitcnt vmcnt(0)" ::: "memory");
    __syncthreads();
    cur ^= 1;
  }

  float* Pp = P + (size_t)ks * (NATOMS * DIM) + (size_t)row0 * DIM + wave * 8;
#pragma unroll
  for (int j = 0; j < 4; ++j) {
    const int r = lane + 64 * j;
    float4 v0 = make_float4(acc[j][0], acc[j][1], acc[j][2], acc[j][3]);
    float4 v1 = make_float4(acc[j][4], acc[j][5], acc[j][6], acc[j][7]);
    *(float4*)(Pp + (size_t)r * DIM) = v0;
    *(float4*)(Pp + (size_t)r * DIM + 4) = v1;
  }
}

// ---------------------------------------------------------------------------
// Gather xs = emb_fp[fingerprints], write to out, and h0 = relu(xs@W0 + b0)
// ---------------------------------------------------------------------------
__global__ __launch_bounds__(256)
void cpi_gather_h(const int* __restrict__ fp, const float* __restrict__ embfp,
                  const float* __restrict__ W, const float* __restrict__ b,
                  float* __restrict__ xs, float* __restrict__ hout) {
  __shared__ float xsl[8][DIM];
  __shared__ float Wl[DIM][DIM];
  const int tid = threadIdx.x;
  const int col = tid & 31;
  const int r8  = tid >> 5;
  const int row = blockIdx.x * 8 + r8;
  const int f   = fp[row];
  const float v = embfp[(size_t)f * DIM + col];
  xs[(size_t)row * DIM + col] = v;
  xsl[r8][col] = v;
#pragma unroll
  for (int i = 0; i < 4; ++i) {
    const int idx = tid + i * 256;
    ((float*)Wl)[idx] = W[idx];
  }
  __syncthreads();
  float a = b[col];
#pragma unroll
  for (int d = 0; d < DIM; ++d) a += xsl[r8][d] * Wl[d][col];
  hout[(size_t)row * DIM + col] = fmaxf(a, 0.f);
}

// ---------------------------------------------------------------------------
// xs += sum_s P[s]; optionally h = relu(xs@W + b) for the next layer
// ---------------------------------------------------------------------------
__global__ __launch_bounds__(256)
void cpi_reduce_h(const float* __restrict__ P, const float* __restrict__ W,
                  const float* __restrict__ b, float* __restrict__ xs,
                  float* __restrict__ hout, const int compute_h) {
  __shared__ float xsl[8][DIM];
  __shared__ float Wl[DIM][DIM];
  const int tid = threadIdx.x;
  const int col = tid & 31;
  const int r8  = tid >> 5;
  const int row = blockIdx.x * 8 + r8;
  const size_t off = (size_t)row * DIM + col;
  float s = xs[off];
#pragma unroll
  for (int k = 0; k < KSPLIT; ++k) s += P[(size_t)k * (NATOMS * DIM) + off];
  xs[off] = s;
  if (compute_h) {  // uniform branch
    xsl[r8][col] = s;
#pragma unroll
    for (int i = 0; i < 4; ++i) {
      const int idx = tid + i * 256;
      ((float*)Wl)[idx] = W[idx];
    }
    __syncthreads();
    float a = b[col];
#pragma unroll
    for (int d = 0; d < DIM; ++d) a += xsl[r8][d] * Wl[d][col];
    hout[off] = fmaxf(a, 0.f);
  }
}

// ---------------------------------------------------------------------------
// word_vectors = emb_word[words]
// ---------------------------------------------------------------------------
__global__ __launch_bounds__(256)
void cpi_words(const int* __restrict__ words, const float* __restrict__ embw,
               float* __restrict__ out) {
  const int i = blockIdx.x * 256 + threadIdx.x;
  const int s = i >> 5;
  const int c = i & 31;
  out[i] = embw[(size_t)words[s] * DIM + c];
}

extern "C" void kernel_launch(void* const* d_in, const int* in_sizes, int n_in,
                              void* d_out, int out_size, void* d_ws, size_t ws_size,
                              hipStream_t stream) {
  const int*   fp    = (const int*)d_in[0];
  const float* adj   = (const float*)d_in[1];
  const int*   words = (const int*)d_in[2];
  const float* embfp = (const float*)d_in[3];
  const float* embw  = (const float*)d_in[4];
  const float* Wg    = (const float*)d_in[5];
  const float* bg    = (const float*)d_in[6];

  float* out = (float*)d_out;
  float* xs  = out;                    // [8192*32] = final compound_vector
  float* wv  = out + NATOMS * DIM;     // [4096*32] word vectors
  float* h   = (float*)d_ws;                  // 1 MB
  float* P   = h + NATOMS * DIM;              // 16 MB split-K partials

  cpi_words<<<dim3(NSEQ * DIM / 256), dim3(256), 0, stream>>>(words, embw, wv);
  cpi_gather_h<<<dim3(NATOMS / 8), dim3(256), 0, stream>>>(fp, embfp, Wg, bg, xs, h);

  for (int l = 0; l < 3; ++l) {
    cpi_gemm<<<dim3(KSPLIT * 32), dim3(256), 0, stream>>>(adj, h, P);
    const float* Wn = (l < 2) ? (Wg + (size_t)(l + 1) * DIM * DIM) : Wg;
    const float* bn = (l < 2) ? (bg + (size_t)(l + 1) * DIM) : bg;
    cpi_reduce_h<<<dim3(NATOMS / 8), dim3(256), 0, stream>>>(
        P, Wn, bn, xs, h, (l < 2) ? 1 : 0);
  }
}

// Round 3
// 244.113 us; speedup vs baseline: 1.3269x; 1.1593x over previous
//
#include <hip/hip_runtime.h>
#include <cstdint>
#include <cstddef>

#define NATOMS 8192
#define DIM 32
#define NSEQ 4096
#define KSPLIT 16
#define BM 256
#define BK 32
#define KPB (NATOMS / KSPLIT)   // 512 k per block
#define NT (KPB / BK)           // 16 tiles

typedef __attribute__((address_space(1))) const void GV;
typedef __attribute__((address_space(3))) void LV;

__device__ __forceinline__ void async16(void* lds, const void* g) {
  __builtin_amdgcn_global_load_lds((GV*)g, (LV*)lds, 16, 0, 0);
}

// ---------------------------------------------------------------------------
// Big GEMM: P[ks] = A[rows, krange] @ h[krange, :]   (fp32, split-K partials)
// Wave w owns output cols [w*8, w*8+8) for ALL 256 rows; lane = row (+64j).
// BOTH A and h tiles are staged via global_load_lds (the only VMEM in the
// loop); compute reads A via swizzled ds_read_b128 (conflict-free) and h via
// wave-uniform ds_read_b128 (broadcast). The compute phase has ZERO vmem ops,
// so the tile t+1 prefetch stays in flight under all of tile t's compute
// (vmcnt FIFO can't force an early drain).
// ---------------------------------------------------------------------------
__global__ __launch_bounds__(256, 2)
void cpi_gemm(const float* __restrict__ A, const float* __restrict__ h,
              float* __restrict__ P) {
  __shared__ float Ab[2][BM * BK];   // 64 KiB, XOR-swizzled chunks
  __shared__ float Hb[2][BK * DIM];  // 8 KiB, linear

  const int tid  = threadIdx.x;
  const int wave = tid >> 6;
  const int lane = tid & 63;
  const int rb   = blockIdx.x & 31;   // row block 0..31
  const int ks   = blockIdx.x >> 5;   // k split 0..15
  const int row0 = rb * BM;
  const int k0   = ks * KPB;

  float acc[4][8];
#pragma unroll
  for (int j = 0; j < 4; ++j)
#pragma unroll
    for (int c = 0; c < 8; ++c) acc[j][c] = 0.f;

  // Stage A tile (32 KB) + h tile (4 KB) with global_load_lds width=16.
  // A: LDS dest linear; global source chunk pre-swizzled: LDS slot s of row r
  // holds global chunk (s ^ (r&7)) -> conflict-free b128 reads later.
  // h: linear both sides; compute reads are wave-uniform (broadcast).
  auto stage = [&](int buf, int t) {
    const int kb = k0 + t * BK;
#pragma unroll
    for (int i = 0; i < 8; ++i) {
      const int D = (wave * 8 + i) * 64 + lane;  // 16B chunk index 0..2047
      const int r = D >> 3;
      const int c = D & 7;
      const float* src =
          A + (size_t)(row0 + r) * NATOMS + kb + ((c ^ (r & 7)) << 2);
      async16(&Ab[buf][(wave * 8 + i) * 256], src);  // wave-uniform lds base
    }
    // h tile: 4 KB = 256 x 16B chunks; wave w covers chunks [w*64, w*64+64)
    const float* hsrc = h + (size_t)kb * DIM + (wave * 64 + lane) * 4;
    async16(&Hb[buf][wave * 256], hsrc);
  };

  stage(0, 0);
  asm volatile("s_waitcnt vmcnt(0)" ::: "memory");
  __syncthreads();

  int cur = 0;
  const int sb = lane & 7;
#pragma unroll 1
  for (int t = 0; t < NT; ++t) {
    if (t + 1 < NT) stage(cur ^ 1, t + 1);  // async prefetch, stays in flight

    const float* Ac = &Ab[cur][0];
    const float* Hc = &Hb[cur][0] + wave * 8;  // this wave's 8 columns

#pragma unroll
    for (int k4 = 0; k4 < 8; ++k4) {
      // 4 k-values x 8 cols of h from LDS, wave-uniform addr -> broadcast
      float4 h0[4], h1[4];
#pragma unroll
      for (int kk = 0; kk < 4; ++kk) {
        const float* hp = Hc + (k4 * 4 + kk) * DIM;
        h0[kk] = *(const float4*)hp;
        h1[kk] = *(const float4*)(hp + 4);
      }

      const int slot = k4 ^ sb;  // swizzled 16B slot holding global chunk k4
      float4 a[4];
#pragma unroll
      for (int j = 0; j < 4; ++j)
        a[j] = *(const float4*)(Ac + (lane + 64 * j) * BK + slot * 4);

#pragma unroll
      for (int j = 0; j < 4; ++j) {
#pragma unroll
        for (int kk = 0; kk < 4; ++kk) {
          const float av = (kk == 0) ? a[j].x
                         : (kk == 1) ? a[j].y
                         : (kk == 2) ? a[j].z : a[j].w;
          acc[j][0] += av * h0[kk].x;
          acc[j][1] += av * h0[kk].y;
          acc[j][2] += av * h0[kk].z;
          acc[j][3] += av * h0[kk].w;
          acc[j][4] += av * h1[kk].x;
          acc[j][5] += av * h1[kk].y;
          acc[j][6] += av * h1[kk].z;
          acc[j][7] += av * h1[kk].w;
        }
      }
    }

    asm volatile("s_waitcnt vmcnt(0)" ::: "memory");
    __syncthreads();
    cur ^= 1;
  }

  float* Pp = P + (size_t)ks * (NATOMS * DIM) + (size_t)row0 * DIM + wave * 8;
#pragma unroll
  for (int j = 0; j < 4; ++j) {
    const int r = lane + 64 * j;
    float4 v0 = make_float4(acc[j][0], acc[j][1], acc[j][2], acc[j][3]);
    float4 v1 = make_float4(acc[j][4], acc[j][5], acc[j][6], acc[j][7]);
    *(float4*)(Pp + (size_t)r * DIM) = v0;
    *(float4*)(Pp + (size_t)r * DIM + 4) = v1;
  }
}

// ---------------------------------------------------------------------------
// Gather xs = emb_fp[fingerprints], write to out, and h0 = relu(xs@W0 + b0)
// ---------------------------------------------------------------------------
__global__ __launch_bounds__(256)
void cpi_gather_h(const int* __restrict__ fp, const float* __restrict__ embfp,
                  const float* __restrict__ W, const float* __restrict__ b,
                  float* __restrict__ xs, float* __restrict__ hout) {
  __shared__ float xsl[8][DIM];
  __shared__ float Wl[DIM][DIM];
  const int tid = threadIdx.x;
  const int col = tid & 31;
  const int r8  = tid >> 5;
  const int row = blockIdx.x * 8 + r8;
  const int f   = fp[row];
  const float v = embfp[(size_t)f * DIM + col];
  xs[(size_t)row * DIM + col] = v;
  xsl[r8][col] = v;
#pragma unroll
  for (int i = 0; i < 4; ++i) {
    const int idx = tid + i * 256;
    ((float*)Wl)[idx] = W[idx];
  }
  __syncthreads();
  float a = b[col];
#pragma unroll
  for (int d = 0; d < DIM; ++d) a += xsl[r8][d] * Wl[d][col];
  hout[(size_t)row * DIM + col] = fmaxf(a, 0.f);
}

// ---------------------------------------------------------------------------
// xs += sum_s P[s]; optionally h = relu(xs@W + b) for the next layer
// ---------------------------------------------------------------------------
__global__ __launch_bounds__(256)
void cpi_reduce_h(const float* __restrict__ P, const float* __restrict__ W,
                  const float* __restrict__ b, float* __restrict__ xs,
                  float* __restrict__ hout, const int compute_h) {
  __shared__ float xsl[8][DIM];
  __shared__ float Wl[DIM][DIM];
  const int tid = threadIdx.x;
  const int col = tid & 31;
  const int r8  = tid >> 5;
  const int row = blockIdx.x * 8 + r8;
  const size_t off = (size_t)row * DIM + col;
  float s = xs[off];
#pragma unroll
  for (int k = 0; k < KSPLIT; ++k) s += P[(size_t)k * (NATOMS * DIM) + off];
  xs[off] = s;
  if (compute_h) {  // uniform branch
    xsl[r8][col] = s;
#pragma unroll
    for (int i = 0; i < 4; ++i) {
      const int idx = tid + i * 256;
      ((float*)Wl)[idx] = W[idx];
    }
    __syncthreads();
    float a = b[col];
#pragma unroll
    for (int d = 0; d < DIM; ++d) a += xsl[r8][d] * Wl[d][col];
    hout[off] = fmaxf(a, 0.f);
  }
}

// ---------------------------------------------------------------------------
// word_vectors = emb_word[words]
// ---------------------------------------------------------------------------
__global__ __launch_bounds__(256)
void cpi_words(const int* __restrict__ words, const float* __restrict__ embw,
               float* __restrict__ out) {
  const int i = blockIdx.x * 256 + threadIdx.x;
  const int s = i >> 5;
  const int c = i & 31;
  out[i] = embw[(size_t)words[s] * DIM + c];
}

extern "C" void kernel_launch(void* const* d_in, const int* in_sizes, int n_in,
                              void* d_out, int out_size, void* d_ws, size_t ws_size,
                              hipStream_t stream) {
  const int*   fp    = (const int*)d_in[0];
  const float* adj   = (const float*)d_in[1];
  const int*   words = (const int*)d_in[2];
  const float* embfp = (const float*)d_in[3];
  const float* embw  = (const float*)d_in[4];
  const float* Wg    = (const float*)d_in[5];
  const float* bg    = (const float*)d_in[6];

  float* out = (float*)d_out;
  float* xs  = out;                    // [8192*32] = final compound_vector
  float* wv  = out + NATOMS * DIM;     // [4096*32] word vectors
  float* h   = (float*)d_ws;                  // 1 MB
  float* P   = h + NATOMS * DIM;              // 16 MB split-K partials

  cpi_words<<<dim3(NSEQ * DIM / 256), dim3(256), 0, stream>>>(words, embw, wv);
  cpi_gather_h<<<dim3(NATOMS / 8), dim3(256), 0, stream>>>(fp, embfp, Wg, bg, xs, h);

  for (int l = 0; l < 3; ++l) {
    cpi_gemm<<<dim3(KSPLIT * 32), dim3(256), 0, stream>>>(adj, h, P);
    const float* Wn = (l < 2) ? (Wg + (size_t)(l + 1) * DIM * DIM) : Wg;
    const float* bn = (l < 2) ? (bg + (size_t)(l + 1) * DIM) : bg;
    cpi_reduce_h<<<dim3(NATOMS / 8), dim3(256), 0, stream>>>(
        P, Wn, bn, xs, h, (l < 2) ? 1 : 0);
  }
}